// Round 3
// baseline (470.056 us; speedup 1.0000x reference)
//
#include <hip/hip_runtime.h>
#include <hip/hip_bf16.h>
#include <stdint.h>

#define S_LEN 2048
#define HID_DIM 2048
#define HQ 32
#define HKV 8
#define NPROJ 5120   // 2048 q | 512 k | 512 v | 2048 g
// Q pre-scale: attention scale * log2(e), so softmax runs in base-2 (v_exp_f32 native)
#define QSCALE_LOG2 (0.125f * 1.44269504088896f)

using f32x4 = __attribute__((ext_vector_type(4))) float;
using bfrag = __attribute__((ext_vector_type(8))) short;

__device__ __forceinline__ unsigned short f2bf(float f) {
    union { float f; unsigned u; } a; a.f = f;
    unsigned r = a.u + 0x7fffu + ((a.u >> 16) & 1u);
    return (unsigned short)(r >> 16);
}
__device__ __forceinline__ float bf2f(unsigned short h) {
    union { unsigned u; float f; } a; a.u = ((unsigned)h) << 16;
    return a.f;
}

// async global->LDS, 16B per lane; LDS dest must be wave-uniform base (+lane*16 implicit)
__device__ __forceinline__ void gload16(const void* g, void* l) {
    __builtin_amdgcn_global_load_lds((const __attribute__((address_space(1))) unsigned int*)g,
                                     (__attribute__((address_space(3))) unsigned int*)l, 16, 0, 0);
}

// ---------------- x fp32 -> bf16 ----------------
__global__ void k_convert_x(const float* __restrict__ x, unsigned short* __restrict__ xb, int n4) {
    int i = blockIdx.x * blockDim.x + threadIdx.x;
    if (i < n4) {
        float4 v = ((const float4*)x)[i];
        ushort4 o;
        o.x = f2bf(v.x); o.y = f2bf(v.y); o.z = f2bf(v.z); o.w = f2bf(v.w);
        ((ushort4*)xb)[i] = o;
    }
}

// ---------------- W [K][N] fp32 -> Wt bf16 [N][K] (at row offset) ----------------
__global__ void k_transpose_w(const float* __restrict__ src, unsigned short* __restrict__ dst,
                              int K, int N, int rowOff) {
    __shared__ float tile[32][33];
    int n0 = blockIdx.x * 32;
    int k0 = blockIdx.y * 32;
    int lx = threadIdx.x & 31;
    int ly = threadIdx.x >> 5;  // 0..7
#pragma unroll
    for (int i = 0; i < 4; i++) {
        int r = ly + i * 8;
        tile[r][lx] = src[(size_t)(k0 + r) * N + n0 + lx];
    }
    __syncthreads();
#pragma unroll
    for (int i = 0; i < 4; i++) {
        int nn = ly + i * 8;
        dst[(size_t)(rowOff + n0 + nn) * K + k0 + lx] = f2bf(tile[lx][nn]);
    }
}

// ---------------- bf16 GEMM (m97 structure): A[M][K] x Bt[N][K] -> C[M][N] fp32 ----------------
// 128x128 tile, BK=64, 4 waves, LINEAR LDS + global_load_lds width-16 staging.
__global__ __launch_bounds__(256) void k_gemm_bf16(
        const unsigned short* __restrict__ A,
        const unsigned short* __restrict__ Bt,
        float* __restrict__ C,
        int M, int N, int K) {
    __shared__ __align__(16) unsigned short As[128 * 64];
    __shared__ __align__(16) unsigned short Bs[128 * 64];
    const int tid = threadIdx.x;
    const int lane = tid & 63;
    const int w = tid >> 6;
    const int wm = (w >> 1) * 64, wn = (w & 1) * 64;
    const int bm0 = blockIdx.y * 128, bn0 = blockIdx.x * 128;
    const int lr = lane & 15;
    const int lk = (lane >> 4) * 8;
    // staging geometry: 1KB chunk = 8 rows x 64 cols (bf16); 16 chunks/matrix; wave w does p*4+w
    const int srow_in = lane >> 3;       // row within chunk (8 lanes per 128B row)
    const int scol = (lane & 7) * 8;     // col (elements)

    f32x4 acc[4][4] = {};

    for (int k0 = 0; k0 < K; k0 += 64) {
        __syncthreads();   // previous tile's reads done before overwrite
#pragma unroll
        for (int p = 0; p < 4; p++) {
            int chunk = p * 4 + w;
            int row = chunk * 8 + srow_in;
            gload16(&A[(size_t)(bm0 + row) * K + k0 + scol], &As[chunk * 512]);
            gload16(&Bt[(size_t)(bn0 + row) * K + k0 + scol], &Bs[chunk * 512]);
        }
        __syncthreads();   // drains vmcnt (global_load_lds) + barrier
#pragma unroll
        for (int kc = 0; kc < 2; kc++) {
            bfrag af[4], bfr[4];
#pragma unroll
            for (int t = 0; t < 4; t++)
                af[t] = *(const bfrag*)&As[(wm + t * 16 + lr) * 64 + kc * 32 + lk];
#pragma unroll
            for (int t = 0; t < 4; t++)
                bfr[t] = *(const bfrag*)&Bs[(wn + t * 16 + lr) * 64 + kc * 32 + lk];
#pragma unroll
            for (int mt = 0; mt < 4; mt++)
#pragma unroll
                for (int nt = 0; nt < 4; nt++)
                    acc[mt][nt] = __builtin_amdgcn_mfma_f32_16x16x32_bf16(af[mt], bfr[nt], acc[mt][nt], 0, 0, 0);
        }
    }
    const int orow = (lane >> 4) * 4;
#pragma unroll
    for (int mt = 0; mt < 4; mt++)
#pragma unroll
        for (int nt = 0; nt < 4; nt++)
#pragma unroll
            for (int j = 0; j < 4; j++)
                C[(size_t)(bm0 + wm + mt * 16 + orow + j) * N + bn0 + wn + nt * 16 + lr] = acc[mt][nt][j];
}

// ---------------- projection epilogue: RoPE / gate / layout shuffles ----------------
__global__ void k_epilogue(const float* __restrict__ proj,
                           const float* __restrict__ cosb, const float* __restrict__ sinb,
                           const float* __restrict__ bg,
                           unsigned short* __restrict__ qb,    // [HQ][S][64], pre-scaled by SCALE*log2e
                           unsigned short* __restrict__ kbuf,  // [HKV][S][64]
                           unsigned short* __restrict__ vt,    // [HKV][64][S]
                           unsigned short* __restrict__ alpha, // [S][2048]
                           float* __restrict__ outk, float* __restrict__ outv) {
    int idx = blockIdx.x * 256 + threadIdx.x;
    int s = idx / NPROJ;
    int n = idx - s * NPROJ;
    float val = proj[idx];
    if (n < 2048) {                 // q + RoPE
        int h = n >> 6, d = n & 63;
        float c = cosb[(s << 6) + d], sn = sinb[(s << 6) + d];
        float partner = proj[(size_t)s * NPROJ + (d < 32 ? n + 32 : n - 32)];
        float rot = (d < 32) ? -partner : partner;
        float o = val * c + rot * sn;
        qb[((size_t)h * S_LEN + s) * 64 + d] = f2bf(o * QSCALE_LOG2);
    } else if (n < 2560) {          // k + RoPE (+ fp32 out)
        int m = n - 2048;
        int h = m >> 6, d = m & 63;
        float c = cosb[(s << 6) + d], sn = sinb[(s << 6) + d];
        float partner = proj[(size_t)s * NPROJ + (d < 32 ? n + 32 : n - 32)];
        float rot = (d < 32) ? -partner : partner;
        float o = val * c + rot * sn;
        size_t oidx = ((size_t)h * S_LEN + s) * 64 + d;
        kbuf[oidx] = f2bf(o);
        outk[oidx] = o;
    } else if (n < 3072) {          // v transposed (+ fp32 out)
        int m = n - 2560;
        int h = m >> 6, d = m & 63;
        vt[((size_t)h * 64 + d) * S_LEN + s] = f2bf(val);
        outv[((size_t)h * S_LEN + s) * 64 + d] = val;
    } else {                        // gate
        int m = n - 3072;
        float a = 1.0f / (1.0f + __expf(-(val + bg[m])));
        alpha[(size_t)s * 2048 + m] = f2bf(a);
    }
}

// ---------------- flash attention (causal, GQA) — wave-independent, no barriers ----------------
// Each wave: 16 q-rows x 2 q-heads (sharing one kv-head). K/V read directly from global (L2-hot).
// Softmax in base-2 (Q pre-scaled by log2e). Per-wave P round-trip through small LDS.
__global__ __launch_bounds__(256) void k_attn(
        const unsigned short* __restrict__ qb,
        const unsigned short* __restrict__ kbuf,
        const unsigned short* __restrict__ vt,
        float* __restrict__ ao) {   // [HQ][S][64]
    __shared__ __align__(16) unsigned short Ps[4][2][16 * 72];  // [wave][head][16 rows][72]
    const int tid = threadIdx.x;
    const int lane = tid & 63;
    const int w = tid >> 6;
    const int lr = lane & 15;
    const int lg = lane >> 4;
    const int lk = lg * 8;

    const int gw = blockIdx.x * 4 + w;       // 0..2047
    const int chunk = 127 - (gw >> 4);       // 0..127, heavy chunks first
    const int rem = gw & 15;
    const int hk = rem >> 1;                 // kv head 0..7
    const int hp = rem & 1;
    const int h0 = hk * 4 + hp;              // two q-heads sharing this kv head
    const int h1 = h0 + 2;
    const int r0 = chunk * 16;
    const int qblk = chunk >> 2;             // last 64-wide KV tile index

    bfrag qf[2][2];
    {
        const unsigned short* q0 = &qb[((size_t)h0 * S_LEN + r0 + lr) * 64];
        const unsigned short* q1 = &qb[((size_t)h1 * S_LEN + r0 + lr) * 64];
        qf[0][0] = *(const bfrag*)&q0[lk];
        qf[0][1] = *(const bfrag*)&q0[32 + lk];
        qf[1][0] = *(const bfrag*)&q1[lk];
        qf[1][1] = *(const bfrag*)&q1[32 + lk];
    }

    f32x4 o_acc[2][4] = {};
    float m_r[2][4], l_r[2][4];
#pragma unroll
    for (int hh = 0; hh < 2; hh++)
#pragma unroll
        for (int j = 0; j < 4; j++) { m_r[hh][j] = -1e30f; l_r[hh][j] = 0.0f; }

    const unsigned short* Kg = &kbuf[(size_t)hk * S_LEN * 64];
    const unsigned short* Vg = &vt[(size_t)hk * 64 * S_LEN];

    for (int kb = 0; kb <= qblk; kb++) {
        const unsigned short* Kt = Kg + (size_t)kb * 64 * 64;
        // ---- QK^T for both heads (K fragment shared) ----
        f32x4 sacc[2][4] = {};
#pragma unroll
        for (int kc = 0; kc < 2; kc++) {
#pragma unroll
            for (int g = 0; g < 4; g++) {
                bfrag kf = *(const bfrag*)&Kt[(size_t)(g * 16 + lr) * 64 + kc * 32 + lk];
                sacc[0][g] = __builtin_amdgcn_mfma_f32_16x16x32_bf16(qf[0][kc], kf, sacc[0][g], 0, 0, 0);
                sacc[1][g] = __builtin_amdgcn_mfma_f32_16x16x32_bf16(qf[1][kc], kf, sacc[1][g], 0, 0, 0);
            }
        }
        if (kb == qblk) {  // diagonal masking (identical for both heads)
#pragma unroll
            for (int g = 0; g < 4; g++)
#pragma unroll
                for (int j = 0; j < 4; j++) {
                    int col = kb * 64 + g * 16 + lr;
                    int row = r0 + lg * 4 + j;
                    if (col > row) { sacc[0][g][j] = -1e30f; sacc[1][g][j] = -1e30f; }
                }
        }
        // ---- online softmax per head (base-2) ----
#pragma unroll
        for (int hh = 0; hh < 2; hh++) {
            float ps[4];
#pragma unroll
            for (int j = 0; j < 4; j++) {
                float tv = fmaxf(fmaxf(sacc[hh][0][j], sacc[hh][1][j]),
                                 fmaxf(sacc[hh][2][j], sacc[hh][3][j]));
#pragma unroll
                for (int msk = 1; msk < 16; msk <<= 1)
                    tv = fmaxf(tv, __shfl_xor(tv, msk, 64));
                float mnew = fmaxf(m_r[hh][j], tv);
                float sc = exp2f(m_r[hh][j] - mnew);
                m_r[hh][j] = mnew;
                l_r[hh][j] *= sc;
#pragma unroll
                for (int g = 0; g < 4; g++) o_acc[hh][g][j] *= sc;
                ps[j] = 0.0f;
            }
#pragma unroll
            for (int g = 0; g < 4; g++)
#pragma unroll
                for (int j = 0; j < 4; j++) {
                    float p = exp2f(sacc[hh][g][j] - m_r[hh][j]);
                    ps[j] += p;
                    Ps[w][hh][(lg * 4 + j) * 72 + g * 16 + lr] = f2bf(p);
                }
#pragma unroll
            for (int j = 0; j < 4; j++) {
                float pv = ps[j];
#pragma unroll
                for (int msk = 1; msk < 16; msk <<= 1)
                    pv += __shfl_xor(pv, msk, 64);
                l_r[hh][j] += pv;
            }
        }
        // ---- P fragments (same-wave LDS round-trip, no barrier) ----
        bfrag pf[2][2];
#pragma unroll
        for (int hh = 0; hh < 2; hh++)
#pragma unroll
            for (int kc = 0; kc < 2; kc++)
                pf[hh][kc] = *(const bfrag*)&Ps[w][hh][lr * 72 + kc * 32 + lk];
        // ---- PV (V fragment shared between heads) ----
        const unsigned short* Vt = Vg + (size_t)kb * 64;
#pragma unroll
        for (int kc = 0; kc < 2; kc++) {
#pragma unroll
            for (int g = 0; g < 4; g++) {
                bfrag vf = *(const bfrag*)&Vt[(size_t)(g * 16 + lr) * S_LEN + kc * 32 + lk];
                o_acc[0][g] = __builtin_amdgcn_mfma_f32_16x16x32_bf16(pf[0][kc], vf, o_acc[0][g], 0, 0, 0);
                o_acc[1][g] = __builtin_amdgcn_mfma_f32_16x16x32_bf16(pf[1][kc], vf, o_acc[1][g], 0, 0, 0);
            }
        }
    }
#pragma unroll
    for (int hh = 0; hh < 2; hh++) {
        const int h = hh ? h1 : h0;
        float inv[4];
#pragma unroll
        for (int j = 0; j < 4; j++) inv[j] = 1.0f / (l_r[hh][j] + 1e-9f);
#pragma unroll
        for (int g = 0; g < 4; g++)
#pragma unroll
            for (int j = 0; j < 4; j++) {
                int row = r0 + lg * 4 + j;
                ao[((size_t)h * S_LEN + row) * 64 + g * 16 + lr] = o_acc[hh][g][j] * inv[j];
            }
    }
}

// ---------------- GroupNorm(D=64) * gate -> bf16 ----------------
__global__ void k_gn(const float* __restrict__ ao, const unsigned short* __restrict__ alpha,
                     const float* __restrict__ gnw, const float* __restrict__ gnb,
                     unsigned short* __restrict__ gno) {
    int row = blockIdx.x * 4 + (threadIdx.x >> 6);  // row = h*2048 + s
    int d = threadIdx.x & 63;
    int h = row >> 11;
    int s = row & 2047;
    float v = ao[(size_t)row * 64 + d];
    float mu = v;
#pragma unroll
    for (int msk = 1; msk < 64; msk <<= 1) mu += __shfl_xor(mu, msk, 64);
    mu *= (1.0f / 64.0f);
    float dv = v - mu;
    float var = dv * dv;
#pragma unroll
    for (int msk = 1; msk < 64; msk <<= 1) var += __shfl_xor(var, msk, 64);
    var *= (1.0f / 64.0f);
    int col = (h << 6) + d;
    float g = dv * rsqrtf(var + 1e-5f) * gnw[col] + gnb[col];
    float a = bf2f(alpha[(size_t)s * 2048 + col]);
    gno[(size_t)s * 2048 + col] = f2bf(g * a);
}

extern "C" void kernel_launch(void* const* d_in, const int* in_sizes, int n_in,
                              void* d_out, int out_size, void* d_ws, size_t ws_size,
                              hipStream_t stream) {
    const float* x   = (const float*)d_in[0];
    const float* rc  = (const float*)d_in[1];
    const float* rs  = (const float*)d_in[2];
    const float* Wq  = (const float*)d_in[3];
    const float* Wk  = (const float*)d_in[4];
    const float* Wv  = (const float*)d_in[5];
    const float* Wo  = (const float*)d_in[6];
    const float* Wg  = (const float*)d_in[7];
    const float* bg  = (const float*)d_in[8];
    const float* gnw = (const float*)d_in[9];
    const float* gnb = (const float*)d_in[10];
    float* out = (float*)d_out;

    char* ws = (char*)d_ws;
    // phase-1 regions
    unsigned short* xb    = (unsigned short*)(ws);                      // 8 MB
    unsigned short* WcatT = (unsigned short*)(ws + 8388608);            // 20 MB, dead after proj GEMM
    unsigned short* WoT   = (unsigned short*)(ws + 29360128);           // 8 MB
    float*          proj  = (float*)(ws + 37748736);                    // 40 MB, dead after epilogue
    // phase-2 regions (reuse WcatT)
    unsigned short* alpha = (unsigned short*)(ws + 8388608);            // 8 MB
    unsigned short* qb    = (unsigned short*)(ws + 16777216);           // 8 MB
    unsigned short* kbuf  = (unsigned short*)(ws + 25165824);           // 2 MB
    unsigned short* vt    = (unsigned short*)(ws + 27262976);           // 2 MB
    // phase-3 regions (reuse proj)
    float*          ao    = (float*)(ws + 37748736);                    // 16 MB
    unsigned short* gno   = (unsigned short*)(ws + 54525952);           // 8 MB

    hipLaunchKernelGGL(k_convert_x, dim3(4096), dim3(256), 0, stream, x, xb, 2048 * 2048 / 4);
    hipLaunchKernelGGL(k_transpose_w, dim3(64, 64), dim3(256), 0, stream, Wq, WcatT, 2048, 2048, 0);
    hipLaunchKernelGGL(k_transpose_w, dim3(16, 64), dim3(256), 0, stream, Wk, WcatT, 2048, 512, 2048);
    hipLaunchKernelGGL(k_transpose_w, dim3(16, 64), dim3(256), 0, stream, Wv, WcatT, 2048, 512, 2560);
    hipLaunchKernelGGL(k_transpose_w, dim3(64, 64), dim3(256), 0, stream, Wg, WcatT, 2048, 2048, 3072);
    hipLaunchKernelGGL(k_transpose_w, dim3(64, 64), dim3(256), 0, stream, Wo, WoT, 2048, 2048, 0);

    hipLaunchKernelGGL(k_gemm_bf16, dim3(5120 / 128, 2048 / 128), dim3(256), 0, stream,
                       xb, WcatT, proj, 2048, 5120, 2048);

    float* outk = out + (size_t)4 * 1024 * 1024;
    float* outv = out + (size_t)5 * 1024 * 1024;
    hipLaunchKernelGGL(k_epilogue, dim3(2048 * 5120 / 256), dim3(256), 0, stream,
                       proj, rc, rs, bg, qb, kbuf, vt, alpha, outk, outv);

    hipLaunchKernelGGL(k_attn, dim3(512), dim3(256), 0, stream, qb, kbuf, vt, ao);

    hipLaunchKernelGGL(k_gn, dim3(32 * 2048 / 4), dim3(256), 0, stream, ao, alpha, gnw, gnb, gno);

    hipLaunchKernelGGL(k_gemm_bf16, dim3(2048 / 128, 2048 / 128), dim3(256), 0, stream,
                       gno, WoT, out, 2048, 2048, 2048);
}

// Round 4
// 376.686 us; speedup vs baseline: 1.2479x; 1.2479x over previous
//
#include <hip/hip_runtime.h>
#include <hip/hip_bf16.h>
#include <stdint.h>

#define S_LEN 2048
#define HID_DIM 2048
#define HQ 32
#define HKV 8
#define NPROJ 5120   // 2048 q | 512 k | 512 v | 2048 g
// Q pre-scale: attention scale * log2(e), so softmax runs in base-2 (v_exp_f32 native)
#define QSCALE_LOG2 (0.125f * 1.44269504088896f)

using f32x4 = __attribute__((ext_vector_type(4))) float;
using bfrag = __attribute__((ext_vector_type(8))) short;

__device__ __forceinline__ unsigned short f2bf(float f) {
    union { float f; unsigned u; } a; a.f = f;
    unsigned r = a.u + 0x7fffu + ((a.u >> 16) & 1u);
    return (unsigned short)(r >> 16);
}
__device__ __forceinline__ float bf2f(unsigned short h) {
    union { unsigned u; float f; } a; a.u = ((unsigned)h) << 16;
    return a.f;
}

// async global->LDS, 16B per lane; LDS dest must be wave-uniform base (+lane*16 implicit)
__device__ __forceinline__ void gload16(const void* g, void* l) {
    __builtin_amdgcn_global_load_lds((const __attribute__((address_space(1))) unsigned int*)g,
                                     (__attribute__((address_space(3))) unsigned int*)l, 16, 0, 0);
}

// ---------------- x fp32 -> bf16 ----------------
__global__ void k_convert_x(const float* __restrict__ x, unsigned short* __restrict__ xb, int n4) {
    int i = blockIdx.x * blockDim.x + threadIdx.x;
    if (i < n4) {
        float4 v = ((const float4*)x)[i];
        ushort4 o;
        o.x = f2bf(v.x); o.y = f2bf(v.y); o.z = f2bf(v.z); o.w = f2bf(v.w);
        ((ushort4*)xb)[i] = o;
    }
}

// ---------------- W [K][N] fp32 -> Wt bf16 [N][K] (at row offset) ----------------
__global__ void k_transpose_w(const float* __restrict__ src, unsigned short* __restrict__ dst,
                              int K, int N, int rowOff) {
    __shared__ float tile[32][33];
    int n0 = blockIdx.x * 32;
    int k0 = blockIdx.y * 32;
    int lx = threadIdx.x & 31;
    int ly = threadIdx.x >> 5;  // 0..7
#pragma unroll
    for (int i = 0; i < 4; i++) {
        int r = ly + i * 8;
        tile[r][lx] = src[(size_t)(k0 + r) * N + n0 + lx];
    }
    __syncthreads();
#pragma unroll
    for (int i = 0; i < 4; i++) {
        int nn = ly + i * 8;
        dst[(size_t)(rowOff + n0 + nn) * K + k0 + lx] = f2bf(tile[lx][nn]);
    }
}

// ---------------- bf16 GEMM (m97 structure): A[M][K] x Bt[N][K] -> C[M][N] fp32 ----------------
// 128x128 tile, BK=64, 4 waves, LINEAR LDS + global_load_lds width-16 staging.
__global__ __launch_bounds__(256) void k_gemm_bf16(
        const unsigned short* __restrict__ A,
        const unsigned short* __restrict__ Bt,
        float* __restrict__ C,
        int M, int N, int K) {
    __shared__ __align__(16) unsigned short As[128 * 64];
    __shared__ __align__(16) unsigned short Bs[128 * 64];
    const int tid = threadIdx.x;
    const int lane = tid & 63;
    const int w = tid >> 6;
    const int wm = (w >> 1) * 64, wn = (w & 1) * 64;
    const int bm0 = blockIdx.y * 128, bn0 = blockIdx.x * 128;
    const int lr = lane & 15;
    const int lk = (lane >> 4) * 8;
    // staging geometry: 1KB chunk = 8 rows x 64 cols (bf16); 16 chunks/matrix; wave w does p*4+w
    const int srow_in = lane >> 3;       // row within chunk (8 lanes per 128B row)
    const int scol = (lane & 7) * 8;     // col (elements)

    f32x4 acc[4][4] = {};

    for (int k0 = 0; k0 < K; k0 += 64) {
        __syncthreads();   // previous tile's reads done before overwrite
#pragma unroll
        for (int p = 0; p < 4; p++) {
            int chunk = p * 4 + w;
            int row = chunk * 8 + srow_in;
            gload16(&A[(size_t)(bm0 + row) * K + k0 + scol], &As[chunk * 512]);
            gload16(&Bt[(size_t)(bn0 + row) * K + k0 + scol], &Bs[chunk * 512]);
        }
        __syncthreads();   // drains vmcnt (global_load_lds) + barrier
#pragma unroll
        for (int kc = 0; kc < 2; kc++) {
            bfrag af[4], bfr[4];
#pragma unroll
            for (int t = 0; t < 4; t++)
                af[t] = *(const bfrag*)&As[(wm + t * 16 + lr) * 64 + kc * 32 + lk];
#pragma unroll
            for (int t = 0; t < 4; t++)
                bfr[t] = *(const bfrag*)&Bs[(wn + t * 16 + lr) * 64 + kc * 32 + lk];
#pragma unroll
            for (int mt = 0; mt < 4; mt++)
#pragma unroll
                for (int nt = 0; nt < 4; nt++)
                    acc[mt][nt] = __builtin_amdgcn_mfma_f32_16x16x32_bf16(af[mt], bfr[nt], acc[mt][nt], 0, 0, 0);
        }
    }
    const int orow = (lane >> 4) * 4;
#pragma unroll
    for (int mt = 0; mt < 4; mt++)
#pragma unroll
        for (int nt = 0; nt < 4; nt++)
#pragma unroll
            for (int j = 0; j < 4; j++)
                C[(size_t)(bm0 + wm + mt * 16 + orow + j) * N + bn0 + wn + nt * 16 + lr] = acc[mt][nt][j];
}

// ---------------- projection epilogue: RoPE / gate / layout shuffles ----------------
__global__ void k_epilogue(const float* __restrict__ proj,
                           const float* __restrict__ cosb, const float* __restrict__ sinb,
                           const float* __restrict__ bg,
                           unsigned short* __restrict__ qb,    // [HQ][S][64], pre-scaled by SCALE*log2e
                           unsigned short* __restrict__ kbuf,  // [HKV][S][64]
                           unsigned short* __restrict__ vt,    // [HKV][64][S]
                           unsigned short* __restrict__ alpha, // [S][2048]
                           float* __restrict__ outk, float* __restrict__ outv) {
    int idx = blockIdx.x * 256 + threadIdx.x;
    int s = idx / NPROJ;
    int n = idx - s * NPROJ;
    float val = proj[idx];
    if (n < 2048) {                 // q + RoPE
        int h = n >> 6, d = n & 63;
        float c = cosb[(s << 6) + d], sn = sinb[(s << 6) + d];
        float partner = proj[(size_t)s * NPROJ + (d < 32 ? n + 32 : n - 32)];
        float rot = (d < 32) ? -partner : partner;
        float o = val * c + rot * sn;
        qb[((size_t)h * S_LEN + s) * 64 + d] = f2bf(o * QSCALE_LOG2);
    } else if (n < 2560) {          // k + RoPE (+ fp32 out)
        int m = n - 2048;
        int h = m >> 6, d = m & 63;
        float c = cosb[(s << 6) + d], sn = sinb[(s << 6) + d];
        float partner = proj[(size_t)s * NPROJ + (d < 32 ? n + 32 : n - 32)];
        float rot = (d < 32) ? -partner : partner;
        float o = val * c + rot * sn;
        size_t oidx = ((size_t)h * S_LEN + s) * 64 + d;
        kbuf[oidx] = f2bf(o);
        outk[oidx] = o;
    } else if (n < 3072) {          // v transposed (+ fp32 out)
        int m = n - 2560;
        int h = m >> 6, d = m & 63;
        vt[((size_t)h * 64 + d) * S_LEN + s] = f2bf(val);
        outv[((size_t)h * S_LEN + s) * 64 + d] = val;
    } else {                        // gate
        int m = n - 3072;
        float a = 1.0f / (1.0f + __expf(-(val + bg[m])));
        alpha[(size_t)s * 2048 + m] = f2bf(a);
    }
}

// ---------------- flash attention (causal, GQA) ----------------
// 2-phase pipelined: double-buffered K/V LDS via async global_load_lds (linear dest,
// pre-swizzled global source; same XOR on ds_read side -> 2-way banks = free).
// Block = 64 q-rows x 1 head, 4 waves x 16 rows. One barrier per KV tile.
__global__ __launch_bounds__(256) void k_attn(
        const unsigned short* __restrict__ qb,
        const unsigned short* __restrict__ kbuf,
        const unsigned short* __restrict__ vt,
        float* __restrict__ ao) {   // [HQ][S][64]
    __shared__ __align__(16) unsigned short Ks[2][64 * 64];
    __shared__ __align__(16) unsigned short Vs[2][64 * 64];
    __shared__ __align__(16) unsigned short Ps[4][16 * 72];
    const int tid = threadIdx.x;
    const int lane = tid & 63;
    const int w = tid >> 6;
    const int lr = lane & 15;
    const int lg = lane >> 4;
    const int lk = lg * 8;

    const int bid = blockIdx.x;
    const int qblk = 31 - (bid >> 5);        // heavy blocks dispatched first
    const int h = bid & 31;
    const int hk = h >> 2;
    const int r0 = qblk * 64 + w * 16;

    // swizzled LDS read offsets (ushort units): frag(g,kc) at Ks[..][g*1024 + lr*64 + swz(kc)]
    const int swzkey = (lr & 7) << 4;                       // byte XOR key = (row&7)<<4
    const int swz0 = ((lg * 16) ^ swzkey) >> 1;             // kc=0
    const int swz1 = ((64 + lg * 16) ^ swzkey) >> 1;        // kc=1
    // staging: lane covers row (lane>>3) of an 8-row chunk, 16B slot (lane&7);
    // global source col pre-swizzled so that linear LDS + swizzled read = identity
    const int srow = lane >> 3;
    const int scol = (((lane & 7) ^ srow) << 3);            // elements

    const unsigned short* Kg = &kbuf[(size_t)hk * S_LEN * 64];
    const unsigned short* Vg = &vt[(size_t)hk * 64 * S_LEN];

    // Q fragments (one-time global read)
    bfrag qf[2];
    {
        const unsigned short* qrow = &qb[((size_t)h * S_LEN + r0 + lr) * 64];
        qf[0] = *(const bfrag*)&qrow[lk];
        qf[1] = *(const bfrag*)&qrow[32 + lk];
    }

    float m_r[4], l_r[4];
    f32x4 o_acc[4] = {};
#pragma unroll
    for (int j = 0; j < 4; j++) { m_r[j] = -1e30f; l_r[j] = 0.0f; }

    // wave w stages K rows [w*16, w*16+16) and V d-rows [w*16, w*16+16) (2 chunks each)
#define STAGE(buf, kb)                                                                  \
    {                                                                                   \
        _Pragma("unroll")                                                               \
        for (int c = 0; c < 2; c++) {                                                   \
            int chunk = w * 2 + c;                                                      \
            gload16(&Kg[(size_t)((kb) * 64 + chunk * 8 + srow) * 64 + scol],            \
                    &Ks[buf][chunk * 512]);                                             \
            gload16(&Vg[(size_t)(chunk * 8 + srow) * S_LEN + (kb) * 64 + scol],         \
                    &Vs[buf][chunk * 512]);                                             \
        }                                                                               \
    }

    const int nt = qblk + 1;
    STAGE(0, 0);
    __syncthreads();
    int cur = 0;

    for (int kb = 0; kb < nt; kb++) {
        if (kb + 1 < nt) STAGE(cur ^ 1, kb + 1);   // async prefetch overlaps compute
        const unsigned short* Kc = Ks[cur];
        const unsigned short* Vc = Vs[cur];
        // ---- QK^T ----
        f32x4 sacc[4] = {};
        __builtin_amdgcn_s_setprio(1);
#pragma unroll
        for (int g = 0; g < 4; g++) {
            bfrag kf0 = *(const bfrag*)&Kc[g * 1024 + lr * 64 + swz0];
            bfrag kf1 = *(const bfrag*)&Kc[g * 1024 + lr * 64 + swz1];
            sacc[g] = __builtin_amdgcn_mfma_f32_16x16x32_bf16(qf[0], kf0, sacc[g], 0, 0, 0);
            sacc[g] = __builtin_amdgcn_mfma_f32_16x16x32_bf16(qf[1], kf1, sacc[g], 0, 0, 0);
        }
        __builtin_amdgcn_s_setprio(0);
        if (kb == qblk) {  // diagonal masking
#pragma unroll
            for (int g = 0; g < 4; g++)
#pragma unroll
                for (int j = 0; j < 4; j++) {
                    int col = kb * 64 + g * 16 + lr;
                    int row = r0 + lg * 4 + j;
                    if (col > row) sacc[g][j] = -1e30f;
                }
        }
        // ---- online softmax (base-2) ----
        float ps[4];
#pragma unroll
        for (int j = 0; j < 4; j++) {
            float tv = fmaxf(fmaxf(sacc[0][j], sacc[1][j]), fmaxf(sacc[2][j], sacc[3][j]));
#pragma unroll
            for (int msk = 1; msk < 16; msk <<= 1)
                tv = fmaxf(tv, __shfl_xor(tv, msk, 64));
            float mnew = fmaxf(m_r[j], tv);
            float sc = exp2f(m_r[j] - mnew);
            m_r[j] = mnew;
            l_r[j] *= sc;
#pragma unroll
            for (int g = 0; g < 4; g++) o_acc[g][j] *= sc;
            ps[j] = 0.0f;
        }
#pragma unroll
        for (int g = 0; g < 4; g++)
#pragma unroll
            for (int j = 0; j < 4; j++) {
                float p = exp2f(sacc[g][j] - m_r[j]);
                ps[j] += p;
                Ps[w][(lg * 4 + j) * 72 + g * 16 + lr] = f2bf(p);
            }
#pragma unroll
        for (int j = 0; j < 4; j++) {
            float pv = ps[j];
#pragma unroll
            for (int msk = 1; msk < 16; msk <<= 1)
                pv += __shfl_xor(pv, msk, 64);
            l_r[j] += pv;
        }
        // ---- P fragments (same-wave LDS round-trip) ----
        bfrag pf0 = *(const bfrag*)&Ps[w][lr * 72 + lk];
        bfrag pf1 = *(const bfrag*)&Ps[w][lr * 72 + 32 + lk];
        // ---- PV ----
        __builtin_amdgcn_s_setprio(1);
#pragma unroll
        for (int g = 0; g < 4; g++) {
            bfrag vf0 = *(const bfrag*)&Vc[g * 1024 + lr * 64 + swz0];
            bfrag vf1 = *(const bfrag*)&Vc[g * 1024 + lr * 64 + swz1];
            o_acc[g] = __builtin_amdgcn_mfma_f32_16x16x32_bf16(pf0, vf0, o_acc[g], 0, 0, 0);
            o_acc[g] = __builtin_amdgcn_mfma_f32_16x16x32_bf16(pf1, vf1, o_acc[g], 0, 0, 0);
        }
        __builtin_amdgcn_s_setprio(0);
        __syncthreads();   // drains vmcnt(0): prefetched tile landed; buffers swappable
        cur ^= 1;
    }
#undef STAGE

    float inv[4];
#pragma unroll
    for (int j = 0; j < 4; j++) inv[j] = 1.0f / (l_r[j] + 1e-9f);
#pragma unroll
    for (int g = 0; g < 4; g++)
#pragma unroll
        for (int j = 0; j < 4; j++) {
            int row = r0 + lg * 4 + j;
            ao[((size_t)h * S_LEN + row) * 64 + g * 16 + lr] = o_acc[g][j] * inv[j];
        }
}

// ---------------- GroupNorm(D=64) * gate -> bf16 ----------------
__global__ void k_gn(const float* __restrict__ ao, const unsigned short* __restrict__ alpha,
                     const float* __restrict__ gnw, const float* __restrict__ gnb,
                     unsigned short* __restrict__ gno) {
    int row = blockIdx.x * 4 + (threadIdx.x >> 6);  // row = h*2048 + s
    int d = threadIdx.x & 63;
    int h = row >> 11;
    int s = row & 2047;
    float v = ao[(size_t)row * 64 + d];
    float mu = v;
#pragma unroll
    for (int msk = 1; msk < 64; msk <<= 1) mu += __shfl_xor(mu, msk, 64);
    mu *= (1.0f / 64.0f);
    float dv = v - mu;
    float var = dv * dv;
#pragma unroll
    for (int msk = 1; msk < 64; msk <<= 1) var += __shfl_xor(var, msk, 64);
    var *= (1.0f / 64.0f);
    int col = (h << 6) + d;
    float g = dv * rsqrtf(var + 1e-5f) * gnw[col] + gnb[col];
    float a = bf2f(alpha[(size_t)s * 2048 + col]);
    gno[(size_t)s * 2048 + col] = f2bf(g * a);
}

extern "C" void kernel_launch(void* const* d_in, const int* in_sizes, int n_in,
                              void* d_out, int out_size, void* d_ws, size_t ws_size,
                              hipStream_t stream) {
    const float* x   = (const float*)d_in[0];
    const float* rc  = (const float*)d_in[1];
    const float* rs  = (const float*)d_in[2];
    const float* Wq  = (const float*)d_in[3];
    const float* Wk  = (const float*)d_in[4];
    const float* Wv  = (const float*)d_in[5];
    const float* Wo  = (const float*)d_in[6];
    const float* Wg  = (const float*)d_in[7];
    const float* bg  = (const float*)d_in[8];
    const float* gnw = (const float*)d_in[9];
    const float* gnb = (const float*)d_in[10];
    float* out = (float*)d_out;

    char* ws = (char*)d_ws;
    // phase-1 regions
    unsigned short* xb    = (unsigned short*)(ws);                      // 8 MB
    unsigned short* WcatT = (unsigned short*)(ws + 8388608);            // 20 MB, dead after proj GEMM
    unsigned short* WoT   = (unsigned short*)(ws + 29360128);           // 8 MB
    float*          proj  = (float*)(ws + 37748736);                    // 40 MB, dead after epilogue
    // phase-2 regions (reuse WcatT)
    unsigned short* alpha = (unsigned short*)(ws + 8388608);            // 8 MB
    unsigned short* qb    = (unsigned short*)(ws + 16777216);           // 8 MB
    unsigned short* kbuf  = (unsigned short*)(ws + 25165824);           // 2 MB
    unsigned short* vt    = (unsigned short*)(ws + 27262976);           // 2 MB
    // phase-3 regions (reuse proj)
    float*          ao    = (float*)(ws + 37748736);                    // 16 MB
    unsigned short* gno   = (unsigned short*)(ws + 54525952);           // 8 MB

    hipLaunchKernelGGL(k_convert_x, dim3(4096), dim3(256), 0, stream, x, xb, 2048 * 2048 / 4);
    hipLaunchKernelGGL(k_transpose_w, dim3(64, 64), dim3(256), 0, stream, Wq, WcatT, 2048, 2048, 0);
    hipLaunchKernelGGL(k_transpose_w, dim3(16, 64), dim3(256), 0, stream, Wk, WcatT, 2048, 512, 2048);
    hipLaunchKernelGGL(k_transpose_w, dim3(16, 64), dim3(256), 0, stream, Wv, WcatT, 2048, 512, 2560);
    hipLaunchKernelGGL(k_transpose_w, dim3(64, 64), dim3(256), 0, stream, Wg, WcatT, 2048, 2048, 3072);
    hipLaunchKernelGGL(k_transpose_w, dim3(64, 64), dim3(256), 0, stream, Wo, WoT, 2048, 2048, 0);

    hipLaunchKernelGGL(k_gemm_bf16, dim3(5120 / 128, 2048 / 128), dim3(256), 0, stream,
                       xb, WcatT, proj, 2048, 5120, 2048);

    float* outk = out + (size_t)4 * 1024 * 1024;
    float* outv = out + (size_t)5 * 1024 * 1024;
    hipLaunchKernelGGL(k_epilogue, dim3(2048 * 5120 / 256), dim3(256), 0, stream,
                       proj, rc, rs, bg, qb, kbuf, vt, alpha, outk, outv);

    hipLaunchKernelGGL(k_attn, dim3(1024), dim3(256), 0, stream, qb, kbuf, vt, ao);

    hipLaunchKernelGGL(k_gn, dim3(32 * 2048 / 4), dim3(256), 0, stream, ao, alpha, gnw, gnb, gno);

    hipLaunchKernelGGL(k_gemm_bf16, dim3(2048 / 128, 2048 / 128), dim3(256), 0, stream,
                       gno, WoT, out, 2048, 2048, 2048);
}